// Round 9
// baseline (907.497 us; speedup 1.0000x reference)
//
#include <hip/hip_runtime.h>
#include <hip/hip_bf16.h>

typedef __attribute__((ext_vector_type(8))) short bf16x8;
typedef __attribute__((ext_vector_type(4))) short s16x4;
typedef __attribute__((ext_vector_type(4))) float f32x4;

#define NW_   3072
#define WACT_ 1536
#define NTOK_ 98304
#define NBLK_ 9830
#define DIM_  384
#define QKVD_ 1152
#define MLPD_ 1536

__device__ __forceinline__ float bf2f(short s) {
  union { unsigned u; float f; } c;
  c.u = ((unsigned)(unsigned short)s) << 16;
  return c.f;
}
__device__ __forceinline__ short f2bf(float f) {
  union { float f; unsigned u; } c; c.f = f;
  unsigned lsb = (c.u >> 16) & 1u;
  c.u += 0x7fffu + lsb;
  return (short)(c.u >> 16);
}

__device__ __forceinline__ f32x4 mfma16(bf16x8 a, bf16x8 b, f32x4 c) {
  return __builtin_amdgcn_mfma_f32_16x16x32_bf16(a, b, c, 0, 0, 0);
}

__device__ __forceinline__ void gload16(const void* g, void* l) {
  __builtin_amdgcn_global_load_lds(
      (const __attribute__((address_space(1))) unsigned*)g,
      (__attribute__((address_space(3))) unsigned*)l, 16, 0, 0);
}

// ---------------- map kernels ----------------
__global__ __launch_bounds__(256) void mapA_k(int* win_rank, unsigned* bitmap) {
  int t = blockIdx.x * 256 + threadIdx.x;
  if (t < NW_) { win_rank[t] = -1; bitmap[t] = 0u; }
}

__global__ __launch_bounds__(256) void mapB_k(const int* __restrict__ iw,
                                              const int* __restrict__ blk,
                                              int* win_rank, unsigned* bitmap) {
  int t = blockIdx.x * 256 + threadIdx.x;
  if (t < WACT_) win_rank[iw[t]] = t;
  if (t < NBLK_) { int j = blk[t]; atomicOr(&bitmap[j >> 5], 1u << (j & 31)); }
}

__global__ __launch_bounds__(256) void mapC_k(const int* __restrict__ ip,
                                              const int* __restrict__ iw,
                                              const unsigned* __restrict__ bitmap,
                                              int* inv_ip, int* rowmap) {
  int i = blockIdx.x * 256 + threadIdx.x;
  if (i < NTOK_) {
    int j = ip[i];
    inv_ip[j] = i;
    int blocked = (bitmap[j >> 5] >> (j & 31)) & 1;
    rowmap[i] = blocked ? -1 : (iw[j >> 6] * 64 + (j & 63));
  }
}

// ---------------- weight conversion ----------------
__global__ __launch_bounds__(256) void wconv_k(const float* __restrict__ qkvw,
                                               const float* __restrict__ projw,
                                               const float* __restrict__ fc1w,
                                               const float* __restrict__ fc2w,
                                               short* __restrict__ dst) {
  int i = blockIdx.x * 256 + threadIdx.x;  // total 1,769,472
  float v;
  if (i < 442368) v = qkvw[i];
  else if (i < 589824) v = projw[i - 442368];
  else if (i < 1179648) v = fc1w[i - 589824];
  else v = fc2w[i - 1179648];
  dst[i] = f2bf(v);
}

// ---------------- LN1 + gather/permute (vectorized: 32 lanes/token) --------
__global__ __launch_bounds__(256) void ln1_k(const float* __restrict__ x,
                                             const float* __restrict__ w,
                                             const float* __restrict__ b,
                                             const int* __restrict__ win_rank,
                                             const int* __restrict__ inv_ip,
                                             const unsigned* __restrict__ bitmap,
                                             float* __restrict__ out,
                                             short* __restrict__ xp) {
  const int l = threadIdx.x & 31;
  const int tok = blockIdx.x * 8 + (threadIdx.x >> 5);
  const f32x4* xr = (const f32x4*)(x + (size_t)tok * DIM_);
  f32x4 v[3]; float s = 0.f;
#pragma unroll
  for (int j = 0; j < 3; ++j) {
    v[j] = xr[l + 32 * j];
    s += v[j][0] + v[j][1] + v[j][2] + v[j][3];
  }
#pragma unroll
  for (int m = 1; m <= 16; m <<= 1) s += __shfl_xor(s, m, 64);
  float mu = s * (1.0f / DIM_);
  float q = 0.f;
#pragma unroll
  for (int j = 0; j < 3; ++j)
#pragma unroll
    for (int e = 0; e < 4; ++e) { float d = v[j][e] - mu; q += d * d; }
#pragma unroll
  for (int m = 1; m <= 16; m <<= 1) q += __shfl_xor(q, m, 64);
  float rs = rsqrtf(q * (1.0f / DIM_) + 1e-5f);
  f32x4 y[3];
#pragma unroll
  for (int j = 0; j < 3; ++j) {
    f32x4 wv = *(const f32x4*)&w[4 * l + 128 * j];
    f32x4 bv = *(const f32x4*)&b[4 * l + 128 * j];
#pragma unroll
    for (int e = 0; e < 4; ++e) y[j][e] = (v[j][e] - mu) * rs * wv[e] + bv[e];
  }
  int wdw = tok >> 6, t = tok & 63;
  int rank = win_rank[wdw];
  if (rank < 0) {
    f32x4* po = (f32x4*)(out + (size_t)tok * DIM_);
#pragma unroll
    for (int j = 0; j < 3; ++j) po[l + 32 * j] = y[j];
  } else {
    int jdx = (rank << 6) + t;
    int i = inv_ip[jdx];
#pragma unroll
    for (int j = 0; j < 3; ++j) {
      s16x4 o;
#pragma unroll
      for (int e = 0; e < 4; ++e) o[e] = f2bf(y[j][e]);
      *(s16x4*)&xp[(size_t)i * DIM_ + 4 * l + 128 * j] = o;
    }
    if ((bitmap[jdx >> 5] >> (jdx & 31)) & 1) {
      f32x4* po = (f32x4*)(out + (size_t)tok * DIM_);
#pragma unroll
      for (int j = 0; j < 3; ++j) po[l + 32 * j] = y[j];
    }
  }
}

// ---------------- LN2 (vectorized: 32 lanes/token, short4) ----------------
__global__ __launch_bounds__(256) void ln2_k(const short* __restrict__ h,
                                             const float* __restrict__ w,
                                             const float* __restrict__ b,
                                             short* __restrict__ outln) {
  const int l = threadIdx.x & 31;
  const int tok = blockIdx.x * 8 + (threadIdx.x >> 5);
  const s16x4* xr = (const s16x4*)(h + (size_t)tok * DIM_);
  float v[12]; float s = 0.f;
#pragma unroll
  for (int j = 0; j < 3; ++j) {
    s16x4 rv = xr[l + 32 * j];
#pragma unroll
    for (int e = 0; e < 4; ++e) { v[j * 4 + e] = bf2f(rv[e]); s += v[j * 4 + e]; }
  }
#pragma unroll
  for (int m = 1; m <= 16; m <<= 1) s += __shfl_xor(s, m, 64);
  float mu = s * (1.0f / DIM_);
  float q = 0.f;
#pragma unroll
  for (int e = 0; e < 12; ++e) { float d = v[e] - mu; q += d * d; }
#pragma unroll
  for (int m = 1; m <= 16; m <<= 1) q += __shfl_xor(q, m, 64);
  float rs = rsqrtf(q * (1.0f / DIM_) + 1e-5f);
  s16x4* po = (s16x4*)(outln + (size_t)tok * DIM_);
#pragma unroll
  for (int j = 0; j < 3; ++j) {
    f32x4 wv = *(const f32x4*)&w[4 * l + 128 * j];
    f32x4 bv = *(const f32x4*)&b[4 * l + 128 * j];
    s16x4 o;
#pragma unroll
    for (int e = 0; e < 4; ++e)
      o[e] = f2bf((v[j * 4 + e] - mu) * rs * wv[e] + bv[e]);
    po[l + 32 * j] = o;
  }
}

// ---------------- GEMM: C = A * B^T (256x128 tile, 8 waves) ----------------
// Single-buffer LDS (48 KB), __syncthreads pipeline, XCD-chunk swizzle.
// EPI 0: +bias -> bf16 (ld N)        (QKV)
// EPI 1: +bias +add_bf -> bf16       (proj + residual -> h)
// EPI 3: +bias +add_bf, scatter fp32 (fc2 + residual -> out)
template <int EPI>
__global__ __launch_bounds__(512) void gemm_k(const short* __restrict__ A,
                                              const short* __restrict__ B,
                                              const float* __restrict__ bias,
                                              int K, int N, int nx,
                                              short* __restrict__ Cb,
                                              const short* __restrict__ add_bf,
                                              const int* __restrict__ rowmap,
                                              float* __restrict__ outf) {
  const int nwg = gridDim.x;
  const int q8 = nwg >> 3;
  const int wg = (blockIdx.x & 7) * q8 + (blockIdx.x >> 3);
  const int ntile = wg % nx, mtile = wg / nx;
  const int tid = threadIdx.x, wid = tid >> 6, lane = tid & 63;
  const int fq = lane >> 4, fr = lane & 15;
  const int wr = wid >> 1, wc = wid & 1;  // 4(M) x 2(N) waves, 64x64 each
  __shared__ __align__(16) short lA[256 * 64];
  __shared__ __align__(16) short lB[128 * 64];
  const int row0 = mtile * 256, col0 = ntile * 128;
  float bs[4];
#pragma unroll
  for (int nt = 0; nt < 4; ++nt) bs[nt] = bias[col0 + wc * 64 + nt * 16 + fr];
  f32x4 acc[4][4];
#pragma unroll
  for (int a = 0; a < 4; ++a)
#pragma unroll
    for (int c = 0; c < 4; ++c) acc[a][c] = (f32x4){0.f, 0.f, 0.f, 0.f};
  const int nkt = K >> 6;
  for (int kt = 0; kt < nkt; ++kt) {
    const int k0 = kt << 6;
#pragma unroll
    for (int i = 0; i < 4; ++i) {
      int g = i * 512 + tid;
      int r = g >> 3, c8 = g & 7;
      int s8 = c8 ^ (r & 7);
      gload16(A + (size_t)(row0 + r) * K + k0 + s8 * 8, (char*)lA + (size_t)g * 16);
    }
#pragma unroll
    for (int i = 0; i < 2; ++i) {
      int g = i * 512 + tid;
      int r = g >> 3, c8 = g & 7;
      int s8 = c8 ^ (r & 7);
      gload16(B + (size_t)(col0 + r) * K + k0 + s8 * 8, (char*)lB + (size_t)g * 16);
    }
    __syncthreads();
#pragma unroll
    for (int ks = 0; ks < 2; ++ks) {
      bf16x8 af[4], bfr[4];
#pragma unroll
      for (int mt = 0; mt < 4; ++mt) {
        int r = wr * 64 + mt * 16 + fr;
        af[mt] = *(const bf16x8*)&lA[r * 64 + ((ks * 4 + fq) ^ (r & 7)) * 8];
      }
#pragma unroll
      for (int nt = 0; nt < 4; ++nt) {
        int r = wc * 64 + nt * 16 + fr;
        bfr[nt] = *(const bf16x8*)&lB[r * 64 + ((ks * 4 + fq) ^ (r & 7)) * 8];
      }
#pragma unroll
      for (int mt = 0; mt < 4; ++mt)
#pragma unroll
        for (int nt = 0; nt < 4; ++nt)
          acc[mt][nt] = mfma16(af[mt], bfr[nt], acc[mt][nt]);
    }
    __syncthreads();
  }
#pragma unroll
  for (int mt = 0; mt < 4; ++mt) {
#pragma unroll
    for (int jj = 0; jj < 4; ++jj) {
      int r = row0 + wr * 64 + mt * 16 + fq * 4 + jj;
      int dmap = 0;
      if (EPI == 3) dmap = rowmap[r];
#pragma unroll
      for (int nt = 0; nt < 4; ++nt) {
        int gcol = col0 + wc * 64 + nt * 16 + fr;
        float v = acc[mt][nt][jj] + bs[nt];
        if (EPI == 0) {
          Cb[(size_t)r * N + gcol] = f2bf(v);
        } else if (EPI == 1) {
          v += bf2f(add_bf[(size_t)r * DIM_ + gcol]);
          Cb[(size_t)r * DIM_ + gcol] = f2bf(v);
        } else {
          v += bf2f(add_bf[(size_t)r * DIM_ + gcol]);
          if (dmap >= 0) outf[(size_t)dmap * DIM_ + gcol] = v;
        }
      }
    }
  }
}

// ---------------- FC1 GEMM: 256x256 tile, 8 waves of 64x128 ----------------
// Single-buffer 64 KB LDS; +bias, fast gelu -> bf16 (ld MLPD_).
__global__ __launch_bounds__(512) void gemm256_k(const short* __restrict__ A,
                                                 const short* __restrict__ B,
                                                 const float* __restrict__ bias,
                                                 int K, int nx,
                                                 short* __restrict__ Cb) {
  const int nwg = gridDim.x;
  const int q8 = nwg >> 3;
  const int wg = (blockIdx.x & 7) * q8 + (blockIdx.x >> 3);
  const int ntile = wg % nx, mtile = wg / nx;
  const int tid = threadIdx.x, wid = tid >> 6, lane = tid & 63;
  const int fq = lane >> 4, fr = lane & 15;
  const int wr = wid >> 1, wc = wid & 1;  // 4(M) x 2(N) waves, 64x128 each
  __shared__ __align__(16) short lA[256 * 64];
  __shared__ __align__(16) short lB[256 * 64];
  const int row0 = mtile * 256, col0 = ntile * 256;
  float bs[8];
#pragma unroll
  for (int nt = 0; nt < 8; ++nt) bs[nt] = bias[col0 + wc * 128 + nt * 16 + fr];
  f32x4 acc[4][8];
#pragma unroll
  for (int a = 0; a < 4; ++a)
#pragma unroll
    for (int c = 0; c < 8; ++c) acc[a][c] = (f32x4){0.f, 0.f, 0.f, 0.f};
  const int nkt = K >> 6;
  for (int kt = 0; kt < nkt; ++kt) {
    const int k0 = kt << 6;
#pragma unroll
    for (int i = 0; i < 4; ++i) {
      int g = i * 512 + tid;
      int r = g >> 3, c8 = g & 7;
      int s8 = c8 ^ (r & 7);
      gload16(A + (size_t)(row0 + r) * K + k0 + s8 * 8, (char*)lA + (size_t)g * 16);
      gload16(B + (size_t)(col0 + r) * K + k0 + s8 * 8, (char*)lB + (size_t)g * 16);
    }
    __syncthreads();
#pragma unroll
    for (int ks = 0; ks < 2; ++ks) {
      bf16x8 af[4], bfr[8];
#pragma unroll
      for (int mt = 0; mt < 4; ++mt) {
        int r = wr * 64 + mt * 16 + fr;
        af[mt] = *(const bf16x8*)&lA[r * 64 + ((ks * 4 + fq) ^ (r & 7)) * 8];
      }
#pragma unroll
      for (int nt = 0; nt < 8; ++nt) {
        int r = wc * 128 + nt * 16 + fr;
        bfr[nt] = *(const bf16x8*)&lB[r * 64 + ((ks * 4 + fq) ^ (r & 7)) * 8];
      }
#pragma unroll
      for (int mt = 0; mt < 4; ++mt)
#pragma unroll
        for (int nt = 0; nt < 8; ++nt)
          acc[mt][nt] = mfma16(af[mt], bfr[nt], acc[mt][nt]);
    }
    __syncthreads();
  }
#pragma unroll
  for (int mt = 0; mt < 4; ++mt) {
#pragma unroll
    for (int jj = 0; jj < 4; ++jj) {
      int r = row0 + wr * 64 + mt * 16 + fq * 4 + jj;
#pragma unroll
      for (int nt = 0; nt < 8; ++nt) {
        int gcol = col0 + wc * 128 + nt * 16 + fr;
        float v = acc[mt][nt][jj] + bs[nt];
        float u = v * (0.79788456f + 0.03567741f * v * v);
        float g = v * __builtin_amdgcn_rcpf(1.0f + __expf(-2.0f * u));
        Cb[(size_t)r * MLPD_ + gcol] = f2bf(g);
      }
    }
  }
}

// ---------------- attention ----------------
__global__ __launch_bounds__(256) void attn_k(const short* __restrict__ qkv,
                                              const unsigned* __restrict__ bitmap,
                                              const int* __restrict__ ip,
                                              short* __restrict__ o) {
  const int m = blockIdx.x;
  const int wid = threadIdx.x >> 6, lane = threadIdx.x & 63;
  const int fq = lane >> 4, fr = lane & 15;
  __shared__ __align__(16) short P[4][64 * 72];
  __shared__ __align__(16) short Vt[4][32 * 72];
  __shared__ unsigned char flags[64];
  if (threadIdx.x < 64) {
    int j = ip[m * 64 + threadIdx.x];
    flags[threadIdx.x] = (unsigned char)((bitmap[j >> 5] >> (j & 31)) & 1);
  }
  __syncthreads();
  const float scale = 0.17677669529663687f;
  int msk[4];
#pragma unroll
  for (int nt = 0; nt < 4; ++nt) msk[nt] = flags[nt * 16 + fr];

  for (int hh = 0; hh < 3; ++hh) {
    int h = wid * 3 + hh;
    const short* base = qkv + (size_t)m * 64 * QKVD_ + h * 96;
    f32x4 sacc[4][4];
#pragma unroll
    for (int a = 0; a < 4; ++a)
#pragma unroll
      for (int c = 0; c < 4; ++c) sacc[a][c] = (f32x4){0.f, 0.f, 0.f, 0.f};
    bf16x8 qa[4], kb[4];
#pragma unroll
    for (int mt = 0; mt < 4; ++mt)
      qa[mt] = *(const bf16x8*)(base + (size_t)(mt * 16 + fr) * QKVD_ + fq * 8);
#pragma unroll
    for (int nt = 0; nt < 4; ++nt)
      kb[nt] = *(const bf16x8*)(base + (size_t)(nt * 16 + fr) * QKVD_ + 32 + fq * 8);
#pragma unroll
    for (int mt = 0; mt < 4; ++mt)
#pragma unroll
      for (int nt = 0; nt < 4; ++nt)
        sacc[mt][nt] = mfma16(qa[mt], kb[nt], sacc[mt][nt]);
#pragma unroll
    for (int c = 0; c < 4; ++c) {
      bf16x8 vv = *(const bf16x8*)(base + (size_t)lane * QKVD_ + 64 + c * 8);
#pragma unroll
      for (int e = 0; e < 8; ++e) Vt[wid][(c * 8 + e) * 72 + lane] = vv[e];
    }
#pragma unroll
    for (int mt = 0; mt < 4; ++mt)
#pragma unroll
      for (int nt = 0; nt < 4; ++nt) {
        f32x4 sv = sacc[mt][nt];
#pragma unroll
        for (int jj = 0; jj < 4; ++jj)
          sv[jj] = msk[nt] ? -10000.0f : sv[jj] * scale;
        sacc[mt][nt] = sv;
      }
#pragma unroll
    for (int mt = 0; mt < 4; ++mt) {
#pragma unroll
      for (int jj = 0; jj < 4; ++jj) {
        float mx = sacc[mt][0][jj];
#pragma unroll
        for (int nt = 1; nt < 4; ++nt) mx = fmaxf(mx, sacc[mt][nt][jj]);
#pragma unroll
        for (int mm = 1; mm < 16; mm <<= 1) mx = fmaxf(mx, __shfl_xor(mx, mm, 64));
        float sm = 0.f;
        float p[4];
#pragma unroll
        for (int nt = 0; nt < 4; ++nt) {
          p[nt] = __expf(sacc[mt][nt][jj] - mx);
          sm += p[nt];
        }
#pragma unroll
        for (int mm = 1; mm < 16; mm <<= 1) sm += __shfl_xor(sm, mm, 64);
        float inv = 1.0f / sm;
        int rowb = (mt * 16 + fq * 4 + jj) * 72;
#pragma unroll
        for (int nt = 0; nt < 4; ++nt)
          P[wid][rowb + nt * 16 + fr] = f2bf(p[nt] * inv);
      }
    }
    f32x4 oacc[4][2];
#pragma unroll
    for (int a = 0; a < 4; ++a)
#pragma unroll
      for (int c = 0; c < 2; ++c) oacc[a][c] = (f32x4){0.f, 0.f, 0.f, 0.f};
#pragma unroll
    for (int ks = 0; ks < 2; ++ks) {
      bf16x8 pa[4], vb[2];
#pragma unroll
      for (int mt = 0; mt < 4; ++mt)
        pa[mt] = *(const bf16x8*)&P[wid][(mt * 16 + fr) * 72 + ks * 32 + fq * 8];
#pragma unroll
      for (int nd = 0; nd < 2; ++nd)
        vb[nd] = *(const bf16x8*)&Vt[wid][(nd * 16 + fr) * 72 + ks * 32 + fq * 8];
#pragma unroll
      for (int mt = 0; mt < 4; ++mt)
#pragma unroll
        for (int nd = 0; nd < 2; ++nd)
          oacc[mt][nd] = mfma16(pa[mt], vb[nd], oacc[mt][nd]);
    }
#pragma unroll
    for (int mt = 0; mt < 4; ++mt)
#pragma unroll
      for (int nd = 0; nd < 2; ++nd)
#pragma unroll
        for (int jj = 0; jj < 4; ++jj)
          o[(size_t)(m * 64 + mt * 16 + fq * 4 + jj) * DIM_ + h * 32 + nd * 16 + fr] =
              f2bf(oacc[mt][nd][jj]);
  }
}

// ---------------- launch ----------------
extern "C" void kernel_launch(void* const* d_in, const int* in_sizes, int n_in,
                              void* d_out, int out_size, void* d_ws, size_t ws_size,
                              hipStream_t stream) {
  const float* x = (const float*)d_in[0];
  const int* iw = (const int*)d_in[1];
  const int* ip = (const int*)d_in[2];
  const int* blk = (const int*)d_in[3];
  const float* ln1w = (const float*)d_in[6];
  const float* ln1b = (const float*)d_in[7];
  const float* qkvw = (const float*)d_in[8];
  const float* qkvb = (const float*)d_in[9];
  const float* projw = (const float*)d_in[10];
  const float* projb = (const float*)d_in[11];
  const float* ln2w = (const float*)d_in[12];
  const float* ln2b = (const float*)d_in[13];
  const float* fc1w = (const float*)d_in[14];
  const float* fc1b = (const float*)d_in[15];
  const float* fc2w = (const float*)d_in[16];
  const float* fc2b = (const float*)d_in[17];
  float* out = (float*)d_out;

  char* ws = (char*)d_ws;
  short* w_all = (short*)ws;                 // 1,769,472 bf16
  short* w_qkv = w_all;
  short* w_proj = w_all + 442368;
  short* w_fc1 = w_all + 589824;
  short* w_fc2 = w_all + 1179648;
  int* inv_ip = (int*)(ws + 3538944);
  int* rowmap = inv_ip + NTOK_;
  int* win_rank = rowmap + NTOK_;
  unsigned* bitmap = (unsigned*)(win_rank + NW_);
  short* xp = (short*)(ws + 4349952);                        // 75.5 MB (also ln2 out)
  short* qkv_g = (short*)(ws + 4349952 + 75497472);          // 302 MB (qkv, then gelu t)
  short* obuf = (short*)(ws + 381837312);                    // 75.5 MB
  short* hbuf = (short*)(ws + 457334784);                    // 75.5 MB
  short* ln2buf = xp;
  (void)in_sizes; (void)n_in; (void)out_size; (void)ws_size;

  mapA_k<<<12, 256, 0, stream>>>(win_rank, bitmap);
  mapB_k<<<39, 256, 0, stream>>>(iw, blk, win_rank, bitmap);
  mapC_k<<<NTOK_ / 256, 256, 0, stream>>>(ip, iw, bitmap, inv_ip, rowmap);
  wconv_k<<<6912, 256, 0, stream>>>(qkvw, projw, fc1w, fc2w, w_all);
  ln1_k<<<(NW_ * 64) / 8, 256, 0, stream>>>(x, ln1w, ln1b, win_rank, inv_ip, bitmap,
                                            out, xp);
  // mtiles = 98304/256 = 384
  gemm_k<0><<<384 * 9, 512, 0, stream>>>(xp, w_qkv, qkvb, 384, QKVD_, 9, qkv_g,
                                         nullptr, nullptr, nullptr);
  attn_k<<<WACT_, 256, 0, stream>>>(qkv_g, bitmap, ip, obuf);
  gemm_k<1><<<384 * 3, 512, 0, stream>>>(obuf, w_proj, projb, 384, DIM_, 3, hbuf,
                                         xp, nullptr, nullptr);
  ln2_k<<<NTOK_ / 8, 256, 0, stream>>>(hbuf, ln2w, ln2b, ln2buf);
  gemm256_k<<<384 * 6, 512, 0, stream>>>(ln2buf, w_fc1, fc1b, 384, 6, qkv_g);
  gemm_k<3><<<384 * 3, 512, 0, stream>>>(qkv_g, w_fc2, fc2b, 1536, DIM_, 3, nullptr,
                                         hbuf, rowmap, out);
}

// Round 10
// 827.969 us; speedup vs baseline: 1.0961x; 1.0961x over previous
//
#include <hip/hip_runtime.h>
#include <hip/hip_bf16.h>

typedef __attribute__((ext_vector_type(8))) short bf16x8;
typedef __attribute__((ext_vector_type(4))) short s16x4;
typedef __attribute__((ext_vector_type(4))) float f32x4;

#define NW_   3072
#define WACT_ 1536
#define NTOK_ 98304
#define NBLK_ 9830
#define DIM_  384
#define QKVD_ 1152
#define MLPD_ 1536

__device__ __forceinline__ float bf2f(short s) {
  union { unsigned u; float f; } c;
  c.u = ((unsigned)(unsigned short)s) << 16;
  return c.f;
}
__device__ __forceinline__ short f2bf(float f) {
  union { float f; unsigned u; } c; c.f = f;
  unsigned lsb = (c.u >> 16) & 1u;
  c.u += 0x7fffu + lsb;
  return (short)(c.u >> 16);
}

__device__ __forceinline__ f32x4 mfma16(bf16x8 a, bf16x8 b, f32x4 c) {
  return __builtin_amdgcn_mfma_f32_16x16x32_bf16(a, b, c, 0, 0, 0);
}

__device__ __forceinline__ void gload16(const void* g, void* l) {
  __builtin_amdgcn_global_load_lds(
      (const __attribute__((address_space(1))) unsigned*)g,
      (__attribute__((address_space(3))) unsigned*)l, 16, 0, 0);
}

// ---------------- map kernels ----------------
__global__ __launch_bounds__(256) void mapA_k(int* win_rank, unsigned* bitmap) {
  int t = blockIdx.x * 256 + threadIdx.x;
  if (t < NW_) { win_rank[t] = -1; bitmap[t] = 0u; }
}

__global__ __launch_bounds__(256) void mapB_k(const int* __restrict__ iw,
                                              const int* __restrict__ blk,
                                              int* win_rank, unsigned* bitmap) {
  int t = blockIdx.x * 256 + threadIdx.x;
  if (t < WACT_) win_rank[iw[t]] = t;
  if (t < NBLK_) { int j = blk[t]; atomicOr(&bitmap[j >> 5], 1u << (j & 31)); }
}

__global__ __launch_bounds__(256) void mapC_k(const int* __restrict__ ip,
                                              const int* __restrict__ iw,
                                              const unsigned* __restrict__ bitmap,
                                              int* inv_ip, int* rowmap) {
  int i = blockIdx.x * 256 + threadIdx.x;
  if (i < NTOK_) {
    int j = ip[i];
    inv_ip[j] = i;
    int blocked = (bitmap[j >> 5] >> (j & 31)) & 1;
    rowmap[i] = blocked ? -1 : (iw[j >> 6] * 64 + (j & 63));
  }
}

// ---------------- weight conversion (vectorized x4) ----------------
__global__ __launch_bounds__(256) void wconv_k(const float* __restrict__ qkvw,
                                               const float* __restrict__ projw,
                                               const float* __restrict__ fc1w,
                                               const float* __restrict__ fc2w,
                                               short* __restrict__ dst) {
  int i = (blockIdx.x * 256 + threadIdx.x) * 4;  // total 1,769,472 elems
  f32x4 v;
  if (i < 442368) v = *(const f32x4*)&qkvw[i];
  else if (i < 589824) v = *(const f32x4*)&projw[i - 442368];
  else if (i < 1179648) v = *(const f32x4*)&fc1w[i - 589824];
  else v = *(const f32x4*)&fc2w[i - 1179648];
  s16x4 o;
#pragma unroll
  for (int e = 0; e < 4; ++e) o[e] = f2bf(v[e]);
  *(s16x4*)&dst[i] = o;
}

// ---------------- LN1 + gather/permute (vectorized: 32 lanes/token) --------
__global__ __launch_bounds__(256) void ln1_k(const float* __restrict__ x,
                                             const float* __restrict__ w,
                                             const float* __restrict__ b,
                                             const int* __restrict__ win_rank,
                                             const int* __restrict__ inv_ip,
                                             const unsigned* __restrict__ bitmap,
                                             float* __restrict__ out,
                                             short* __restrict__ xp) {
  const int l = threadIdx.x & 31;
  const int tok = blockIdx.x * 8 + (threadIdx.x >> 5);
  const f32x4* xr = (const f32x4*)(x + (size_t)tok * DIM_);
  f32x4 v[3]; float s = 0.f;
#pragma unroll
  for (int j = 0; j < 3; ++j) {
    v[j] = xr[l + 32 * j];
    s += v[j][0] + v[j][1] + v[j][2] + v[j][3];
  }
#pragma unroll
  for (int m = 1; m <= 16; m <<= 1) s += __shfl_xor(s, m, 64);
  float mu = s * (1.0f / DIM_);
  float q = 0.f;
#pragma unroll
  for (int j = 0; j < 3; ++j)
#pragma unroll
    for (int e = 0; e < 4; ++e) { float d = v[j][e] - mu; q += d * d; }
#pragma unroll
  for (int m = 1; m <= 16; m <<= 1) q += __shfl_xor(q, m, 64);
  float rs = rsqrtf(q * (1.0f / DIM_) + 1e-5f);
  f32x4 y[3];
#pragma unroll
  for (int j = 0; j < 3; ++j) {
    f32x4 wv = *(const f32x4*)&w[4 * l + 128 * j];
    f32x4 bv = *(const f32x4*)&b[4 * l + 128 * j];
#pragma unroll
    for (int e = 0; e < 4; ++e) y[j][e] = (v[j][e] - mu) * rs * wv[e] + bv[e];
  }
  int wdw = tok >> 6, t = tok & 63;
  int rank = win_rank[wdw];
  if (rank < 0) {
    f32x4* po = (f32x4*)(out + (size_t)tok * DIM_);
#pragma unroll
    for (int j = 0; j < 3; ++j) po[l + 32 * j] = y[j];
  } else {
    int jdx = (rank << 6) + t;
    int i = inv_ip[jdx];
#pragma unroll
    for (int j = 0; j < 3; ++j) {
      s16x4 o;
#pragma unroll
      for (int e = 0; e < 4; ++e) o[e] = f2bf(y[j][e]);
      *(s16x4*)&xp[(size_t)i * DIM_ + 4 * l + 128 * j] = o;
    }
    if ((bitmap[jdx >> 5] >> (jdx & 31)) & 1) {
      f32x4* po = (f32x4*)(out + (size_t)tok * DIM_);
#pragma unroll
      for (int j = 0; j < 3; ++j) po[l + 32 * j] = y[j];
    }
  }
}

// ---------------- LN2 (vectorized: 32 lanes/token, short4) ----------------
__global__ __launch_bounds__(256) void ln2_k(const short* __restrict__ h,
                                             const float* __restrict__ w,
                                             const float* __restrict__ b,
                                             short* __restrict__ outln) {
  const int l = threadIdx.x & 31;
  const int tok = blockIdx.x * 8 + (threadIdx.x >> 5);
  const s16x4* xr = (const s16x4*)(h + (size_t)tok * DIM_);
  float v[12]; float s = 0.f;
#pragma unroll
  for (int j = 0; j < 3; ++j) {
    s16x4 rv = xr[l + 32 * j];
#pragma unroll
    for (int e = 0; e < 4; ++e) { v[j * 4 + e] = bf2f(rv[e]); s += v[j * 4 + e]; }
  }
#pragma unroll
  for (int m = 1; m <= 16; m <<= 1) s += __shfl_xor(s, m, 64);
  float mu = s * (1.0f / DIM_);
  float q = 0.f;
#pragma unroll
  for (int e = 0; e < 12; ++e) { float d = v[e] - mu; q += d * d; }
#pragma unroll
  for (int m = 1; m <= 16; m <<= 1) q += __shfl_xor(q, m, 64);
  float rs = rsqrtf(q * (1.0f / DIM_) + 1e-5f);
  s16x4* po = (s16x4*)(outln + (size_t)tok * DIM_);
#pragma unroll
  for (int j = 0; j < 3; ++j) {
    f32x4 wv = *(const f32x4*)&w[4 * l + 128 * j];
    f32x4 bv = *(const f32x4*)&b[4 * l + 128 * j];
    s16x4 o;
#pragma unroll
    for (int e = 0; e < 4; ++e)
      o[e] = f2bf((v[j * 4 + e] - mu) * rs * wv[e] + bv[e]);
    po[l + 32 * j] = o;
  }
}

// ---------------- GEMM: C = A * B^T (256x128 tile, 8 waves) ----------------
// Single-buffer LDS (48 KB -> 3 blocks/CU), __syncthreads pipeline,
// XCD-chunk swizzle, bias in regs. (Proven R8 structure.)
// EPI 0: +bias -> bf16 (ld N)        (QKV)
// EPI 1: +bias +add_bf -> bf16       (proj + residual -> h)
// EPI 2: +bias, fast gelu -> bf16    (fc1)
// EPI 3: +bias +add_bf, scatter fp32 (fc2 + residual -> out)
template <int EPI>
__global__ __launch_bounds__(512) void gemm_k(const short* __restrict__ A,
                                              const short* __restrict__ B,
                                              const float* __restrict__ bias,
                                              int K, int N, int nx,
                                              short* __restrict__ Cb,
                                              const short* __restrict__ add_bf,
                                              const int* __restrict__ rowmap,
                                              float* __restrict__ outf) {
  const int nwg = gridDim.x;
  const int q8 = nwg >> 3;
  const int wg = (blockIdx.x & 7) * q8 + (blockIdx.x >> 3);
  const int ntile = wg % nx, mtile = wg / nx;
  const int tid = threadIdx.x, wid = tid >> 6, lane = tid & 63;
  const int fq = lane >> 4, fr = lane & 15;
  const int wr = wid >> 1, wc = wid & 1;  // 4(M) x 2(N) waves, 64x64 each
  __shared__ __align__(16) short lA[256 * 64];
  __shared__ __align__(16) short lB[128 * 64];
  const int row0 = mtile * 256, col0 = ntile * 128;
  float bs[4];
#pragma unroll
  for (int nt = 0; nt < 4; ++nt) bs[nt] = bias[col0 + wc * 64 + nt * 16 + fr];
  f32x4 acc[4][4];
#pragma unroll
  for (int a = 0; a < 4; ++a)
#pragma unroll
    for (int c = 0; c < 4; ++c) acc[a][c] = (f32x4){0.f, 0.f, 0.f, 0.f};
  const int nkt = K >> 6;
  for (int kt = 0; kt < nkt; ++kt) {
    const int k0 = kt << 6;
#pragma unroll
    for (int i = 0; i < 4; ++i) {
      int g = i * 512 + tid;
      int r = g >> 3, c8 = g & 7;
      int s8 = c8 ^ (r & 7);
      gload16(A + (size_t)(row0 + r) * K + k0 + s8 * 8, (char*)lA + (size_t)g * 16);
    }
#pragma unroll
    for (int i = 0; i < 2; ++i) {
      int g = i * 512 + tid;
      int r = g >> 3, c8 = g & 7;
      int s8 = c8 ^ (r & 7);
      gload16(B + (size_t)(col0 + r) * K + k0 + s8 * 8, (char*)lB + (size_t)g * 16);
    }
    __syncthreads();
#pragma unroll
    for (int ks = 0; ks < 2; ++ks) {
      bf16x8 af[4], bfr[4];
#pragma unroll
      for (int mt = 0; mt < 4; ++mt) {
        int r = wr * 64 + mt * 16 + fr;
        af[mt] = *(const bf16x8*)&lA[r * 64 + ((ks * 4 + fq) ^ (r & 7)) * 8];
      }
#pragma unroll
      for (int nt = 0; nt < 4; ++nt) {
        int r = wc * 64 + nt * 16 + fr;
        bfr[nt] = *(const bf16x8*)&lB[r * 64 + ((ks * 4 + fq) ^ (r & 7)) * 8];
      }
#pragma unroll
      for (int mt = 0; mt < 4; ++mt)
#pragma unroll
        for (int nt = 0; nt < 4; ++nt)
          acc[mt][nt] = mfma16(af[mt], bfr[nt], acc[mt][nt]);
    }
    __syncthreads();
  }
#pragma unroll
  for (int mt = 0; mt < 4; ++mt) {
#pragma unroll
    for (int jj = 0; jj < 4; ++jj) {
      int r = row0 + wr * 64 + mt * 16 + fq * 4 + jj;
      int dmap = 0;
      if (EPI == 3) dmap = rowmap[r];
#pragma unroll
      for (int nt = 0; nt < 4; ++nt) {
        int gcol = col0 + wc * 64 + nt * 16 + fr;
        float v = acc[mt][nt][jj] + bs[nt];
        if (EPI == 0) {
          Cb[(size_t)r * N + gcol] = f2bf(v);
        } else if (EPI == 1) {
          v += bf2f(add_bf[(size_t)r * DIM_ + gcol]);
          Cb[(size_t)r * DIM_ + gcol] = f2bf(v);
        } else if (EPI == 2) {
          // gelu(x) ~= x * sigmoid(2u), u = 0.79788456*(x + 0.044715 x^3)
          float u = v * (0.79788456f + 0.03567741f * v * v);
          float g = v * __builtin_amdgcn_rcpf(1.0f + __expf(-2.0f * u));
          Cb[(size_t)r * MLPD_ + gcol] = f2bf(g);
        } else {
          v += bf2f(add_bf[(size_t)r * DIM_ + gcol]);
          if (dmap >= 0) outf[(size_t)dmap * DIM_ + gcol] = v;
        }
      }
    }
  }
}

// ---------------- attention: one head per wave ----------------
// grid = WACT_ * 3; block bid handles m = bid/3, head group g = bid%3;
// wave wid computes head h = g*4 + wid. No serial per-wave head loop.
__global__ __launch_bounds__(256) void attn_k(const short* __restrict__ qkv,
                                              const unsigned* __restrict__ bitmap,
                                              const int* __restrict__ ip,
                                              short* __restrict__ o) {
  const int m = blockIdx.x / 3;
  const int h = (blockIdx.x % 3) * 4 + (threadIdx.x >> 6);
  const int wid = threadIdx.x >> 6, lane = threadIdx.x & 63;
  const int fq = lane >> 4, fr = lane & 15;
  __shared__ __align__(16) short P[4][64 * 72];
  __shared__ __align__(16) short Vt[4][32 * 72];
  __shared__ unsigned char flags[64];
  if (threadIdx.x < 64) {
    int j = ip[m * 64 + threadIdx.x];
    flags[threadIdx.x] = (unsigned char)((bitmap[j >> 5] >> (j & 31)) & 1);
  }
  __syncthreads();
  const float scale = 0.17677669529663687f;
  int msk[4];
#pragma unroll
  for (int nt = 0; nt < 4; ++nt) msk[nt] = flags[nt * 16 + fr];

  const short* base = qkv + (size_t)m * 64 * QKVD_ + h * 96;
  // ---- S = Q K^T ----
  f32x4 sacc[4][4];
#pragma unroll
  for (int a = 0; a < 4; ++a)
#pragma unroll
    for (int c = 0; c < 4; ++c) sacc[a][c] = (f32x4){0.f, 0.f, 0.f, 0.f};
  bf16x8 qa[4], kb[4];
#pragma unroll
  for (int mt = 0; mt < 4; ++mt)
    qa[mt] = *(const bf16x8*)(base + (size_t)(mt * 16 + fr) * QKVD_ + fq * 8);
#pragma unroll
  for (int nt = 0; nt < 4; ++nt)
    kb[nt] = *(const bf16x8*)(base + (size_t)(nt * 16 + fr) * QKVD_ + 32 + fq * 8);
#pragma unroll
  for (int mt = 0; mt < 4; ++mt)
#pragma unroll
    for (int nt = 0; nt < 4; ++nt)
      sacc[mt][nt] = mfma16(qa[mt], kb[nt], sacc[mt][nt]);
  // ---- stage V transposed ----
#pragma unroll
  for (int c = 0; c < 4; ++c) {
    bf16x8 vv = *(const bf16x8*)(base + (size_t)lane * QKVD_ + 64 + c * 8);
#pragma unroll
    for (int e = 0; e < 8; ++e) Vt[wid][(c * 8 + e) * 72 + lane] = vv[e];
  }
  // ---- scale + mask ----
#pragma unroll
  for (int mt = 0; mt < 4; ++mt)
#pragma unroll
    for (int nt = 0; nt < 4; ++nt) {
      f32x4 sv = sacc[mt][nt];
#pragma unroll
      for (int jj = 0; jj < 4; ++jj)
        sv[jj] = msk[nt] ? -10000.0f : sv[jj] * scale;
      sacc[mt][nt] = sv;
    }
  // ---- softmax rows + write P ----
#pragma unroll
  for (int mt = 0; mt < 4; ++mt) {
#pragma unroll
    for (int jj = 0; jj < 4; ++jj) {
      float mx = sacc[mt][0][jj];
#pragma unroll
      for (int nt = 1; nt < 4; ++nt) mx = fmaxf(mx, sacc[mt][nt][jj]);
#pragma unroll
      for (int mm = 1; mm < 16; mm <<= 1) mx = fmaxf(mx, __shfl_xor(mx, mm, 64));
      float sm = 0.f;
      float p[4];
#pragma unroll
      for (int nt = 0; nt < 4; ++nt) {
        p[nt] = __expf(sacc[mt][nt][jj] - mx);
        sm += p[nt];
      }
#pragma unroll
      for (int mm = 1; mm < 16; mm <<= 1) sm += __shfl_xor(sm, mm, 64);
      float inv = 1.0f / sm;
      int rowb = (mt * 16 + fq * 4 + jj) * 72;
#pragma unroll
      for (int nt = 0; nt < 4; ++nt)
        P[wid][rowb + nt * 16 + fr] = f2bf(p[nt] * inv);
    }
  }
  // ---- O = P V ----
  f32x4 oacc[4][2];
#pragma unroll
  for (int a = 0; a < 4; ++a)
#pragma unroll
    for (int c = 0; c < 2; ++c) oacc[a][c] = (f32x4){0.f, 0.f, 0.f, 0.f};
#pragma unroll
  for (int ks = 0; ks < 2; ++ks) {
    bf16x8 pa[4], vb[2];
#pragma unroll
    for (int mt = 0; mt < 4; ++mt)
      pa[mt] = *(const bf16x8*)&P[wid][(mt * 16 + fr) * 72 + ks * 32 + fq * 8];
#pragma unroll
    for (int nd = 0; nd < 2; ++nd)
      vb[nd] = *(const bf16x8*)&Vt[wid][(nd * 16 + fr) * 72 + ks * 32 + fq * 8];
#pragma unroll
    for (int mt = 0; mt < 4; ++mt)
#pragma unroll
      for (int nd = 0; nd < 2; ++nd)
        oacc[mt][nd] = mfma16(pa[mt], vb[nd], oacc[mt][nd]);
  }
  // ---- store O ----
#pragma unroll
  for (int mt = 0; mt < 4; ++mt)
#pragma unroll
    for (int nd = 0; nd < 2; ++nd)
#pragma unroll
      for (int jj = 0; jj < 4; ++jj)
        o[(size_t)(m * 64 + mt * 16 + fq * 4 + jj) * DIM_ + h * 32 + nd * 16 + fr] =
            f2bf(oacc[mt][nd][jj]);
}

// ---------------- launch ----------------
extern "C" void kernel_launch(void* const* d_in, const int* in_sizes, int n_in,
                              void* d_out, int out_size, void* d_ws, size_t ws_size,
                              hipStream_t stream) {
  const float* x = (const float*)d_in[0];
  const int* iw = (const int*)d_in[1];
  const int* ip = (const int*)d_in[2];
  const int* blk = (const int*)d_in[3];
  const float* ln1w = (const float*)d_in[6];
  const float* ln1b = (const float*)d_in[7];
  const float* qkvw = (const float*)d_in[8];
  const float* qkvb = (const float*)d_in[9];
  const float* projw = (const float*)d_in[10];
  const float* projb = (const float*)d_in[11];
  const float* ln2w = (const float*)d_in[12];
  const float* ln2b = (const float*)d_in[13];
  const float* fc1w = (const float*)d_in[14];
  const float* fc1b = (const float*)d_in[15];
  const float* fc2w = (const float*)d_in[16];
  const float* fc2b = (const float*)d_in[17];
  float* out = (float*)d_out;

  char* ws = (char*)d_ws;
  short* w_all = (short*)ws;                 // 1,769,472 bf16
  short* w_qkv = w_all;
  short* w_proj = w_all + 442368;
  short* w_fc1 = w_all + 589824;
  short* w_fc2 = w_all + 1179648;
  int* inv_ip = (int*)(ws + 3538944);
  int* rowmap = inv_ip + NTOK_;
  int* win_rank = rowmap + NTOK_;
  unsigned* bitmap = (unsigned*)(win_rank + NW_);
  short* xp = (short*)(ws + 4349952);                        // 75.5 MB (also ln2 out)
  short* qkv_g = (short*)(ws + 4349952 + 75497472);          // 302 MB (qkv, then gelu t)
  short* obuf = (short*)(ws + 381837312);                    // 75.5 MB
  short* hbuf = (short*)(ws + 457334784);                    // 75.5 MB
  short* ln2buf = xp;
  (void)in_sizes; (void)n_in; (void)out_size; (void)ws_size;

  mapA_k<<<12, 256, 0, stream>>>(win_rank, bitmap);
  mapB_k<<<39, 256, 0, stream>>>(iw, blk, win_rank, bitmap);
  mapC_k<<<NTOK_ / 256, 256, 0, stream>>>(ip, iw, bitmap, inv_ip, rowmap);
  wconv_k<<<1728, 256, 0, stream>>>(qkvw, projw, fc1w, fc2w, w_all);
  ln1_k<<<(NW_ * 64) / 8, 256, 0, stream>>>(x, ln1w, ln1b, win_rank, inv_ip, bitmap,
                                            out, xp);
  // mtiles = 98304/256 = 384
  gemm_k<0><<<384 * 9, 512, 0, stream>>>(xp, w_qkv, qkvb, 384, QKVD_, 9, qkv_g,
                                         nullptr, nullptr, nullptr);
  attn_k<<<WACT_ * 3, 256, 0, stream>>>(qkv_g, bitmap, ip, obuf);
  gemm_k<1><<<384 * 3, 512, 0, stream>>>(obuf, w_proj, projb, 384, DIM_, 3, hbuf,
                                         xp, nullptr, nullptr);
  ln2_k<<<NTOK_ / 8, 256, 0, stream>>>(hbuf, ln2w, ln2b, ln2buf);
  gemm_k<2><<<384 * 12, 512, 0, stream>>>(ln2buf, w_fc1, fc1b, 384, MLPD_, 12, qkv_g,
                                          nullptr, nullptr, nullptr);
  gemm_k<3><<<384 * 3, 512, 0, stream>>>(qkv_g, w_fc2, fc2b, 1536, DIM_, 3, nullptr,
                                         hbuf, rowmap, out);
}